// Round 1
// baseline (9377.844 us; speedup 1.0000x reference)
//
#include <hip/hip_runtime.h>
#include <hip/hip_bf16.h>
#include <math.h>

#define TT   512
#define CC   768
#define HH   12
#define HSZ  64
#define LL   12
#define C4   3072
#define BTOT 2048   // B*T

// ---------------------------------------------------------------- embedding
__global__ __launch_bounds__(256) void embed_k(const int* __restrict__ idx,
    const float* __restrict__ tok, const float* __restrict__ pos,
    float* __restrict__ x)
{
    int r   = blockIdx.x;            // token row 0..2047
    int tid = threadIdx.x;
    int t   = r & (TT - 1);
    long id = idx[r];
    const float* te = tok + id * (long)CC;
    const float* pe = pos + (long)t * CC;
    float* xr = x + (long)r * CC;
#pragma unroll
    for (int i = 0; i < 3; ++i) {
        int c = tid + i * 256;
        xr[c] = te[c] + pe[c];
    }
}

// ---------------------------------------------------------------- layernorm
__global__ __launch_bounds__(256) void ln_k(const float* __restrict__ x,
    const float* __restrict__ g, const float* __restrict__ b,
    float* __restrict__ y)
{
    int r = blockIdx.x, tid = threadIdx.x;
    const float* xr = x + (long)r * CC;
    float v[3];
    v[0] = xr[tid]; v[1] = xr[tid + 256]; v[2] = xr[tid + 512];
    float s  = v[0] + v[1] + v[2];
    float sq = v[0]*v[0] + v[1]*v[1] + v[2]*v[2];
#pragma unroll
    for (int off = 32; off > 0; off >>= 1) {
        s  += __shfl_down(s, off);
        sq += __shfl_down(sq, off);
    }
    __shared__ float ss[4], ssq[4];
    int w = tid >> 6;
    if ((tid & 63) == 0) { ss[w] = s; ssq[w] = sq; }
    __syncthreads();
    s  = ss[0] + ss[1] + ss[2] + ss[3];
    sq = ssq[0] + ssq[1] + ssq[2] + ssq[3];
    float mean = s * (1.0f / CC);
    float var  = sq * (1.0f / CC) - mean * mean;
    float rs   = rsqrtf(var + 1e-5f);
    float* yr = y + (long)r * CC;
#pragma unroll
    for (int i = 0; i < 3; ++i) {
        int c = tid + i * 256;
        yr[c] = (v[i] - mean) * rs * g[c] + b[c];
    }
}

// ---------------------------------------------------------------- GEMM
// C[M,N] (= / epilogue) A[M,K] @ B[K,N]; row-major; M%64==0, N%64==0, K%16==0.
// EPI: 0 = store, 2 = bias + exact-GELU, 3 = in-place residual add + bias.
// blockIdx.z batches B and C by sBz/sCz elements (per-head QKV).
template <int EPI>
__global__ __launch_bounds__(256) void gemm_k(const float* __restrict__ A,
    const float* __restrict__ B, float* __restrict__ C,
    const float* __restrict__ bias, int K, int lda, int ldb, int ldc,
    long sBz, long sCz)
{
    __shared__ float As[16][64];
    __shared__ float Bs[16][64];
    B += (long)blockIdx.z * sBz;
    C += (long)blockIdx.z * sCz;
    const int row0 = blockIdx.y * 64;
    const int col0 = blockIdx.x * 64;
    const int tid  = threadIdx.x;
    const int tx = tid & 15, ty = tid >> 4;

    // staging indices
    const int ar = tid >> 2, ac = (tid & 3) * 4;    // A: 64 rows x 16 cols
    const int br = tid >> 4, bc = (tid & 15) * 4;   // B: 16 rows x 64 cols
    const float* Aptr = A + (long)(row0 + ar) * lda + ac;
    const float* Bptr = B + (long)br * ldb + col0 + bc;

    float acc[4][4] = {};
    for (int k0 = 0; k0 < K; k0 += 16) {
        float4 av = *(const float4*)Aptr;
        float4 bv = *(const float4*)Bptr;
        Aptr += 16;
        Bptr += (long)16 * ldb;
        __syncthreads();
        As[ac + 0][ar] = av.x; As[ac + 1][ar] = av.y;
        As[ac + 2][ar] = av.z; As[ac + 3][ar] = av.w;
        *(float4*)&Bs[br][bc] = bv;
        __syncthreads();
#pragma unroll
        for (int kk = 0; kk < 16; ++kk) {
            float4 aq = *(const float4*)&As[kk][ty * 4];
            float4 bq = *(const float4*)&Bs[kk][tx * 4];
            float a[4] = {aq.x, aq.y, aq.z, aq.w};
            float bb[4] = {bq.x, bq.y, bq.z, bq.w};
#pragma unroll
            for (int i = 0; i < 4; ++i)
#pragma unroll
                for (int j = 0; j < 4; ++j)
                    acc[i][j] = fmaf(a[i], bb[j], acc[i][j]);
        }
    }

    const long crow = row0 + ty * 4;
    const long ccol = col0 + tx * 4;
    float4 bvv = make_float4(0.f, 0.f, 0.f, 0.f);
    if (EPI == 2 || EPI == 3) bvv = *(const float4*)&bias[ccol];
#pragma unroll
    for (int i = 0; i < 4; ++i) {
        float* cp = C + (crow + i) * ldc + ccol;
        if (EPI == 0) {
            *(float4*)cp = make_float4(acc[i][0], acc[i][1], acc[i][2], acc[i][3]);
        } else if (EPI == 2) {
            float t0 = acc[i][0] + bvv.x, t1 = acc[i][1] + bvv.y;
            float t2 = acc[i][2] + bvv.z, t3 = acc[i][3] + bvv.w;
            t0 = 0.5f * t0 * (1.0f + erff(t0 * 0.70710678118654752f));
            t1 = 0.5f * t1 * (1.0f + erff(t1 * 0.70710678118654752f));
            t2 = 0.5f * t2 * (1.0f + erff(t2 * 0.70710678118654752f));
            t3 = 0.5f * t3 * (1.0f + erff(t3 * 0.70710678118654752f));
            *(float4*)cp = make_float4(t0, t1, t2, t3);
        } else { // EPI == 3
            float4 old = *(const float4*)cp;
            *(float4*)cp = make_float4(old.x + acc[i][0] + bvv.x,
                                       old.y + acc[i][1] + bvv.y,
                                       old.z + acc[i][2] + bvv.z,
                                       old.w + acc[i][3] + bvv.w);
        }
    }
}

// ---------------------------------------------------------------- attention
// q,k,v laid out as [H][B*T][64]; one wave (64 threads) per (b,h,t).
// Online softmax over causal prefix; writes o as [B*T, 768].
__global__ __launch_bounds__(64) void attn_k(const float* __restrict__ q,
    const float* __restrict__ k, const float* __restrict__ v,
    float* __restrict__ o)
{
    const int gid = blockIdx.x;          // ((b*H + h)*T + t)
    const int t   = gid & (TT - 1);
    const int bh  = gid >> 9;
    const int h   = bh % HH;
    const int b   = bh / HH;
    const int lane = threadIdx.x;

    const long base = ((long)h * BTOT + (long)b * TT) * HSZ;
    const float* qr = q + base + (long)t * HSZ;

    float qreg[HSZ];
#pragma unroll
    for (int i = 0; i < 16; ++i) {
        float4 qv = ((const float4*)qr)[i];
        qreg[4*i+0] = qv.x; qreg[4*i+1] = qv.y;
        qreg[4*i+2] = qv.z; qreg[4*i+3] = qv.w;
    }

    const float scale = 0.125f;          // 64^-0.5
    float m = -INFINITY, l = 0.f, oacc = 0.f;

    for (int c0 = 0; c0 <= t; c0 += 64) {
        int s = c0 + lane;
        float sc = -INFINITY;
        if (s <= t) {
            const float4* kr = (const float4*)(k + base + (long)s * HSZ);
            float d = 0.f;
#pragma unroll
            for (int i = 0; i < 16; ++i) {
                float4 kv = kr[i];
                d = fmaf(qreg[4*i+0], kv.x, d);
                d = fmaf(qreg[4*i+1], kv.y, d);
                d = fmaf(qreg[4*i+2], kv.z, d);
                d = fmaf(qreg[4*i+3], kv.w, d);
            }
            sc = d * scale;
        }
        float cm = sc;
#pragma unroll
        for (int off = 32; off > 0; off >>= 1)
            cm = fmaxf(cm, __shfl_xor(cm, off));
        float mn   = fmaxf(m, cm);
        float corr = __expf(m - mn);     // first chunk: exp(-inf) = 0
        float p    = (s <= t) ? __expf(sc - mn) : 0.f;
        float psum = p;
#pragma unroll
        for (int off = 32; off > 0; off >>= 1)
            psum += __shfl_xor(psum, off);
        l = l * corr + psum;
        oacc *= corr;
        const float* vb = v + base + (long)c0 * HSZ + lane;
#pragma unroll 8
        for (int ss = 0; ss < 64; ++ss) {
            float pp = __shfl(p, ss);
            oacc = fmaf(pp, vb[(long)ss * HSZ], oacc);
        }
        m = mn;
    }
    o[((long)(b * TT + t)) * CC + h * HSZ + lane] = oacc / l;
}

// ---------------------------------------------------------------- final LN + head
__global__ __launch_bounds__(256) void head_k(const float* __restrict__ x,
    const float* __restrict__ g, const float* __restrict__ bb,
    const float* __restrict__ Wh, const float* __restrict__ bh,
    float* __restrict__ out)
{
    int r = blockIdx.x, tid = threadIdx.x;
    const float* xr = x + (long)r * CC;
    float v[3];
    v[0] = xr[tid]; v[1] = xr[tid + 256]; v[2] = xr[tid + 512];
    float s  = v[0] + v[1] + v[2];
    float sq = v[0]*v[0] + v[1]*v[1] + v[2]*v[2];
#pragma unroll
    for (int off = 32; off > 0; off >>= 1) {
        s  += __shfl_down(s, off);
        sq += __shfl_down(sq, off);
    }
    __shared__ float ss[4], ssq[4];
    int w = tid >> 6;
    if ((tid & 63) == 0) { ss[w] = s; ssq[w] = sq; }
    __syncthreads();
    s  = ss[0] + ss[1] + ss[2] + ss[3];
    sq = ssq[0] + ssq[1] + ssq[2] + ssq[3];
    float mean = s * (1.0f / CC);
    float var  = sq * (1.0f / CC) - mean * mean;
    float rs   = rsqrtf(var + 1e-5f);

    float acc[16];
#pragma unroll
    for (int j = 0; j < 16; ++j) acc[j] = 0.f;
#pragma unroll
    for (int i = 0; i < 3; ++i) {
        int c = tid + i * 256;
        float xnv = (v[i] - mean) * rs * g[c] + bb[c];
        const float* wr = Wh + (long)c * 16;
#pragma unroll
        for (int j = 0; j < 16; ++j) acc[j] = fmaf(xnv, wr[j], acc[j]);
    }
#pragma unroll
    for (int off = 32; off > 0; off >>= 1)
#pragma unroll
        for (int j = 0; j < 16; ++j) acc[j] += __shfl_down(acc[j], off);
    __shared__ float red[4][16];
    if ((tid & 63) == 0)
#pragma unroll
        for (int j = 0; j < 16; ++j) red[w][j] = acc[j];
    __syncthreads();
    if (tid < 16)
        out[(long)r * 16 + tid] =
            red[0][tid] + red[1][tid] + red[2][tid] + red[3][tid] + bh[tid];
}

// ---------------------------------------------------------------- launch
extern "C" void kernel_launch(void* const* d_in, const int* in_sizes, int n_in,
                              void* d_out, int out_size, void* d_ws, size_t ws_size,
                              hipStream_t stream)
{
    const int*   idx  = (const int*)  d_in[0];
    const float* tok  = (const float*)d_in[1];
    const float* pos  = (const float*)d_in[2];
    const float* Wq   = (const float*)d_in[3];
    const float* Wk   = (const float*)d_in[4];
    const float* Wv   = (const float*)d_in[5];
    const float* Wo   = (const float*)d_in[6];
    const float* bo   = (const float*)d_in[7];
    const float* W1   = (const float*)d_in[8];
    const float* b1   = (const float*)d_in[9];
    const float* W2   = (const float*)d_in[10];
    const float* b2   = (const float*)d_in[11];
    const float* ln1g = (const float*)d_in[12];
    const float* ln1b = (const float*)d_in[13];
    const float* ln2g = (const float*)d_in[14];
    const float* ln2b = (const float*)d_in[15];
    const float* lnfg = (const float*)d_in[16];
    const float* lnfb = (const float*)d_in[17];
    const float* Wh   = (const float*)d_in[18];
    const float* bh   = (const float*)d_in[19];

    float* ws = (float*)d_ws;
    const long NX = (long)BTOT * CC;          // 1572864
    float* x  = ws;
    float* xn = ws + 1 * NX;
    float* q  = ws + 2 * NX;
    float* k  = ws + 3 * NX;
    float* v  = ws + 4 * NX;
    float* o  = ws + 5 * NX;
    float* hb = ws + 6 * NX;                  // [2048, 3072]

    embed_k<<<BTOT, 256, 0, stream>>>(idx, tok, pos, x);

    const long wAtt = (long)HH * CC * HSZ;    // per-layer Wq/Wk/Wv size
    for (int l = 0; l < LL; ++l) {
        ln_k<<<BTOT, 256, 0, stream>>>(x, ln1g + l * CC, ln1b + l * CC, xn);

        dim3 gqkv(1, BTOT / 64, HH);
        gemm_k<0><<<gqkv, 256, 0, stream>>>(xn, Wq + (long)l * wAtt, q, nullptr,
            CC, CC, HSZ, HSZ, (long)CC * HSZ, (long)BTOT * HSZ);
        gemm_k<0><<<gqkv, 256, 0, stream>>>(xn, Wk + (long)l * wAtt, k, nullptr,
            CC, CC, HSZ, HSZ, (long)CC * HSZ, (long)BTOT * HSZ);
        gemm_k<0><<<gqkv, 256, 0, stream>>>(xn, Wv + (long)l * wAtt, v, nullptr,
            CC, CC, HSZ, HSZ, (long)CC * HSZ, (long)BTOT * HSZ);

        attn_k<<<4 * HH * TT, 64, 0, stream>>>(q, k, v, o);

        gemm_k<3><<<dim3(CC / 64, BTOT / 64, 1), 256, 0, stream>>>(
            o, Wo + (long)l * CC * CC, x, bo + (long)l * CC,
            CC, CC, CC, CC, 0, 0);

        ln_k<<<BTOT, 256, 0, stream>>>(x, ln2g + l * CC, ln2b + l * CC, xn);

        gemm_k<2><<<dim3(C4 / 64, BTOT / 64, 1), 256, 0, stream>>>(
            xn, W1 + (long)l * CC * C4, hb, b1 + (long)l * C4,
            CC, CC, C4, C4, 0, 0);

        gemm_k<3><<<dim3(CC / 64, BTOT / 64, 1), 256, 0, stream>>>(
            hb, W2 + (long)l * C4 * CC, x, b2 + (long)l * CC,
            C4, C4, CC, CC, 0, 0);
    }

    head_k<<<BTOT, 256, 0, stream>>>(x, lnfg, lnfb, Wh, bh, (float*)d_out);
}

// Round 2
// 2266.650 us; speedup vs baseline: 4.1373x; 4.1373x over previous
//
#include <hip/hip_runtime.h>
#include <hip/hip_bf16.h>
#include <math.h>

#define TT   512
#define CC   768
#define HH   12
#define HSZ  64
#define LL   12
#define C4   3072
#define BTOT 2048   // B*T
#define NQKV 2304   // 3*C

typedef __attribute__((ext_vector_type(8))) short short8;
typedef __attribute__((ext_vector_type(4))) float f32x4;

__device__ __forceinline__ unsigned f2b_bits(float f) {
    unsigned u = __float_as_uint(f);
    return (u + 0x7fffu + ((u >> 16) & 1u)) >> 16;
}

// ---------------------------------------------------------------- embedding
__global__ __launch_bounds__(256) void embed_k(const int* __restrict__ idx,
    const float* __restrict__ tok, const float* __restrict__ pos,
    float* __restrict__ x)
{
    int r   = blockIdx.x;
    int tid = threadIdx.x;
    int t   = r & (TT - 1);
    long id = idx[r];
    const float* te = tok + id * (long)CC;
    const float* pe = pos + (long)t * CC;
    float* xr = x + (long)r * CC;
#pragma unroll
    for (int i = 0; i < 3; ++i) {
        int c = tid + i * 256;
        xr[c] = te[c] + pe[c];
    }
}

// ---------------------------------------------------------------- layernorm (fp32 in, bf16 out)
__global__ __launch_bounds__(256) void ln_b(const float* __restrict__ x,
    const float* __restrict__ g, const float* __restrict__ b,
    __hip_bfloat16* __restrict__ y)
{
    int r = blockIdx.x, tid = threadIdx.x;
    const float* xr = x + (long)r * CC;
    float v[3];
    v[0] = xr[tid]; v[1] = xr[tid + 256]; v[2] = xr[tid + 512];
    float s  = v[0] + v[1] + v[2];
    float sq = v[0]*v[0] + v[1]*v[1] + v[2]*v[2];
#pragma unroll
    for (int off = 32; off > 0; off >>= 1) {
        s  += __shfl_down(s, off);
        sq += __shfl_down(sq, off);
    }
    __shared__ float ss[4], ssq[4];
    int w = tid >> 6;
    if ((tid & 63) == 0) { ss[w] = s; ssq[w] = sq; }
    __syncthreads();
    s  = ss[0] + ss[1] + ss[2] + ss[3];
    sq = ssq[0] + ssq[1] + ssq[2] + ssq[3];
    float mean = s * (1.0f / CC);
    float var  = sq * (1.0f / CC) - mean * mean;
    float rs   = rsqrtf(var + 1e-5f);
    __hip_bfloat16* yr = y + (long)r * CC;
#pragma unroll
    for (int i = 0; i < 3; ++i) {
        int c = tid + i * 256;
        yr[c] = __float2bfloat16((v[i] - mean) * rs * g[c] + b[c]);
    }
}

// ------------------------------------------------- weight convert/transpose
// generic: src fp32 [R][D] -> dst bf16 [D][R]; grid (D/64, R/64)
__global__ __launch_bounds__(256) void cvtT_k(const float* __restrict__ src,
    __hip_bfloat16* __restrict__ dst, int R, int D)
{
    __shared__ __hip_bfloat16 t[64][65];
    int d0 = blockIdx.x * 64, r0 = blockIdx.y * 64;
    int tid = threadIdx.x;
#pragma unroll
    for (int i = 0; i < 16; ++i) {
        int flat = tid + i * 256, r = flat >> 6, c = flat & 63;
        t[c][r] = __float2bfloat16(src[(long)(r0 + r) * D + d0 + c]);
    }
    __syncthreads();
#pragma unroll
    for (int i = 0; i < 16; ++i) {
        int flat = tid + i * 256, dr = flat >> 6, rr = flat & 63;
        dst[(long)(d0 + dr) * R + r0 + rr] = t[dr][rr];
    }
}

// Wq/Wk/Wv [h][768][64] (layer-offset) -> WqkvT [2304][768]; grid (12, 36)
__global__ __launch_bounds__(256) void cvt_qkvT(const float* __restrict__ Wq,
    const float* __restrict__ Wk, const float* __restrict__ Wv,
    __hip_bfloat16* __restrict__ out)
{
    __shared__ __hip_bfloat16 t[64][65];
    int g = blockIdx.y;
    int c0 = blockIdx.x * 64;
    int which = g / 12, h = g % 12;
    const float* src = (which == 0 ? Wq : which == 1 ? Wk : Wv)
                       + (long)h * CC * HSZ;
    int nb = which * CC + h * HSZ;
    int tid = threadIdx.x;
#pragma unroll
    for (int i = 0; i < 16; ++i) {
        int flat = tid + i * 256, r = flat >> 6, d = flat & 63;
        t[d][r] = __float2bfloat16(src[(long)(c0 + r) * HSZ + d]);
    }
    __syncthreads();
#pragma unroll
    for (int i = 0; i < 16; ++i) {
        int flat = tid + i * 256, dr = flat >> 6, rr = flat & 63;
        out[(long)(nb + dr) * CC + c0 + rr] = t[dr][rr];
    }
}

// V slice of qkv [2048][2304] -> vT [B][H][64][512]; grid (8, 12, 4)
__global__ __launch_bounds__(256) void cvt_v(const __hip_bfloat16* __restrict__ qkv,
    __hip_bfloat16* __restrict__ vT)
{
    __shared__ __hip_bfloat16 t[64][65];
    int t0 = blockIdx.x * 64, h = blockIdx.y, b = blockIdx.z;
    int tid = threadIdx.x;
#pragma unroll
    for (int i = 0; i < 16; ++i) {
        int flat = tid + i * 256, r = flat >> 6, c = flat & 63;
        t[c][r] = qkv[(long)(b * TT + t0 + r) * NQKV + 2 * CC + h * HSZ + c];
    }
    __syncthreads();
#pragma unroll
    for (int i = 0; i < 16; ++i) {
        int flat = tid + i * 256, dc = flat >> 6, rr = flat & 63;
        vT[((long)((b * HH + h) * HSZ + dc)) * TT + t0 + rr] = t[dc][rr];
    }
}

// ---------------------------------------------------------------- bf16 MFMA GEMM
// C[M,N] = A[M,K] @ B[K,N], A bf16 [M][lda], BT bf16 [N][ldb] (=B^T), K%32==0.
// Tile 128x128, BK=32, 256 threads (4 waves, 2x2 wave grid, 64x64 per wave).
// EPI 0: store bf16; EPI 2: +bias, exact GELU, store bf16; EPI 3: resid fp32 += acc+bias.
template <int EPI>
__global__ __launch_bounds__(256) void gemm_bf16(
    const __hip_bfloat16* __restrict__ A,
    const __hip_bfloat16* __restrict__ BT,
    __hip_bfloat16* __restrict__ Cb, float* __restrict__ Cf,
    const float* __restrict__ bias,
    int K, int lda, int ldb, int ldc)
{
    __shared__ short Asm[128 * 32];
    __shared__ short Bsm[128 * 32];
    const int tid  = threadIdx.x;
    const int lane = tid & 63;
    const int wid  = tid >> 6;
    const int wm = wid >> 1, wn = wid & 1;
    const int row0 = blockIdx.y * 128, col0 = blockIdx.x * 128;

    const int s_r = tid >> 2;          // 0..63
    const int s_k = (tid & 3) * 8;     // 0,8,16,24
    const __hip_bfloat16* Ap = A  + (long)(row0 + s_r) * lda + s_k;
    const __hip_bfloat16* Bp = BT + (long)(col0 + s_r) * ldb + s_k;

    f32x4 acc[4][4] = {};
    short8 a0, a1, b0, b1;
    a0 = *(const short8*)Ap;              a1 = *(const short8*)(Ap + (long)64 * lda);
    b0 = *(const short8*)Bp;              b1 = *(const short8*)(Bp + (long)64 * ldb);

    for (int k0 = 0; k0 < K; k0 += 32) {
        __syncthreads();
        *(short8*)&Asm[s_r * 32 + s_k]        = a0;
        *(short8*)&Asm[(64 + s_r) * 32 + s_k] = a1;
        *(short8*)&Bsm[s_r * 32 + s_k]        = b0;
        *(short8*)&Bsm[(64 + s_r) * 32 + s_k] = b1;
        __syncthreads();
        if (k0 + 32 < K) {
            Ap += 32; Bp += 32;
            a0 = *(const short8*)Ap;      a1 = *(const short8*)(Ap + (long)64 * lda);
            b0 = *(const short8*)Bp;      b1 = *(const short8*)(Bp + (long)64 * ldb);
        }
        const int fr = lane & 15, g8 = (lane >> 4) * 8;
        short8 af[4], bf[4];
#pragma unroll
        for (int m = 0; m < 4; ++m)
            af[m] = *(const short8*)&Asm[(wm * 64 + m * 16 + fr) * 32 + g8];
#pragma unroll
        for (int n = 0; n < 4; ++n)
            bf[n] = *(const short8*)&Bsm[(wn * 64 + n * 16 + fr) * 32 + g8];
#pragma unroll
        for (int m = 0; m < 4; ++m)
#pragma unroll
            for (int n = 0; n < 4; ++n)
                acc[m][n] = __builtin_amdgcn_mfma_f32_16x16x32_bf16(
                    af[m], bf[n], acc[m][n], 0, 0, 0);
    }

    const int fr = lane & 15, fq = lane >> 4;
#pragma unroll
    for (int m = 0; m < 4; ++m) {
        int rbase = row0 + wm * 64 + m * 16 + fq * 4;
#pragma unroll
        for (int n = 0; n < 4; ++n) {
            int col = col0 + wn * 64 + n * 16 + fr;
            float bv = (EPI == 0) ? 0.f : bias[col];
#pragma unroll
            for (int j = 0; j < 4; ++j) {
                long row = rbase + j;
                float v = acc[m][n][j];
                if (EPI == 0) {
                    Cb[row * ldc + col] = __float2bfloat16(v);
                } else if (EPI == 2) {
                    v += bv;
                    v = 0.5f * v * (1.0f + erff(v * 0.70710678118654752f));
                    Cb[row * ldc + col] = __float2bfloat16(v);
                } else {
                    Cf[row * ldc + col] += v + bv;
                }
            }
        }
    }
}

// ---------------------------------------------------------------- MFMA flash attention
// qkv [2048][2304] bf16 (q|k|v cols, col=h*64+d), vT [B][H][64][512] bf16.
// One wave per (b,h,16-query tile). S^T = mfma(K, Q) -> q index is lane-local.
__global__ __launch_bounds__(64) void attn_mfma(
    const __hip_bfloat16* __restrict__ qkv,
    const __hip_bfloat16* __restrict__ vT,
    __hip_bfloat16* __restrict__ o)
{
    const int qt = blockIdx.x;    // 0..31
    const int h  = blockIdx.y;    // 0..11
    const int b  = blockIdx.z;    // 0..3
    const int lane = threadIdx.x;
    const int t0 = qt * 16;
    const int fr = lane & 15, g = lane >> 4;

    __shared__ unsigned short P_lds[16 * 40];   // [q][40] padded, conflict-lite
    __shared__ float corr_lds[16], l_lds[16];

    // Q as B-operand: n=q=fr, k=d=g*8+i (+32 second k-step)
    const long qbase = ((long)(b * TT + t0 + fr)) * NQKV + h * HSZ + g * 8;
    short8 qf0 = *(const short8*)(qkv + qbase);
    short8 qf1 = *(const short8*)(qkv + qbase + 32);

    f32x4 oacc[4] = {};
    float m_run = -3.0e38f, l_run = 0.f;
    const int t_lane = t0 + fr;
    const int smax = t0 + 15;

    for (int s0 = 0; s0 <= smax; s0 += 32) {
        // S^T for two 16-key subtiles
        f32x4 st[2];
#pragma unroll
        for (int sub = 0; sub < 2; ++sub) {
            const long kbase = ((long)(b * TT + s0 + sub * 16 + fr)) * NQKV
                               + CC + h * HSZ + g * 8;
            short8 kf0 = *(const short8*)(qkv + kbase);
            short8 kf1 = *(const short8*)(qkv + kbase + 32);
            f32x4 z = {};
            z = __builtin_amdgcn_mfma_f32_16x16x32_bf16(kf0, qf0, z, 0, 0, 0);
            z = __builtin_amdgcn_mfma_f32_16x16x32_bf16(kf1, qf1, z, 0, 0, 0);
            st[sub] = z;
        }
        // scale + causal mask + online softmax stats (q = fr column, lane-local)
        float p[8];
        float mx = -3.0e38f;
#pragma unroll
        for (int sub = 0; sub < 2; ++sub)
#pragma unroll
            for (int j = 0; j < 4; ++j) {
                int s = s0 + sub * 16 + g * 4 + j;
                float v = st[sub][j] * 0.125f;
                v = (s <= t_lane) ? v : -3.0e38f;
                p[sub * 4 + j] = v;
                mx = fmaxf(mx, v);
            }
        mx = fmaxf(mx, __shfl_xor(mx, 16));
        mx = fmaxf(mx, __shfl_xor(mx, 32));
        float mnew = fmaxf(m_run, mx);
        float corr = __expf(m_run - mnew);
        float psum = 0.f;
#pragma unroll
        for (int i = 0; i < 8; ++i) {
            float e = __expf(p[i] - mnew);
            p[i] = e; psum += e;
        }
        psum += __shfl_xor(psum, 16);
        psum += __shfl_xor(psum, 32);
        l_run = l_run * corr + psum;
        m_run = mnew;

        __syncthreads();   // WAR: previous iteration's P/corr reads done
        if (lane < 16) corr_lds[lane] = corr;
        // pack P^T values into P[q][s_local] (bf16 pairs)
        unsigned u0 = f2b_bits(p[0]) | (f2b_bits(p[1]) << 16);
        unsigned u1 = f2b_bits(p[2]) | (f2b_bits(p[3]) << 16);
        unsigned u2 = f2b_bits(p[4]) | (f2b_bits(p[5]) << 16);
        unsigned u3 = f2b_bits(p[6]) | (f2b_bits(p[7]) << 16);
        *(unsigned*)&P_lds[fr * 40 + g * 4]          = u0;
        *(unsigned*)&P_lds[fr * 40 + g * 4 + 2]      = u1;
        *(unsigned*)&P_lds[fr * 40 + 16 + g * 4]     = u2;
        *(unsigned*)&P_lds[fr * 40 + 16 + g * 4 + 2] = u3;
        __syncthreads();

        // rescale O (rows are q = g*4+j here)
        float cr0 = corr_lds[g * 4 + 0], cr1 = corr_lds[g * 4 + 1];
        float cr2 = corr_lds[g * 4 + 2], cr3 = corr_lds[g * 4 + 3];
        short8 pf = *(const short8*)&P_lds[fr * 40 + g * 8];
#pragma unroll
        for (int dt = 0; dt < 4; ++dt) {
            oacc[dt][0] *= cr0; oacc[dt][1] *= cr1;
            oacc[dt][2] *= cr2; oacc[dt][3] *= cr3;
            const long vbase = (((long)(b * HH + h) * HSZ) + dt * 16 + fr) * TT
                               + s0 + g * 8;
            short8 vf = *(const short8*)(vT + vbase);
            oacc[dt] = __builtin_amdgcn_mfma_f32_16x16x32_bf16(pf, vf, oacc[dt], 0, 0, 0);
        }
    }

    __syncthreads();
    if (lane < 16) l_lds[lane] = l_run;
    __syncthreads();
    float il0 = 1.f / l_lds[g * 4 + 0], il1 = 1.f / l_lds[g * 4 + 1];
    float il2 = 1.f / l_lds[g * 4 + 2], il3 = 1.f / l_lds[g * 4 + 3];
#pragma unroll
    for (int dt = 0; dt < 4; ++dt) {
        long cbase = (long)(b * TT + t0) * CC + h * HSZ + dt * 16 + fr;
        o[cbase + 0 * CC + (g * 4 + 0) * (long)CC] = __float2bfloat16(oacc[dt][0] * il0);
        o[cbase + 0 * CC + (g * 4 + 1) * (long)CC] = __float2bfloat16(oacc[dt][1] * il1);
        o[cbase + 0 * CC + (g * 4 + 2) * (long)CC] = __float2bfloat16(oacc[dt][2] * il2);
        o[cbase + 0 * CC + (g * 4 + 3) * (long)CC] = __float2bfloat16(oacc[dt][3] * il3);
    }
}

// ---------------------------------------------------------------- final LN + head
__global__ __launch_bounds__(256) void head_k(const float* __restrict__ x,
    const float* __restrict__ g, const float* __restrict__ bb,
    const float* __restrict__ Wh, const float* __restrict__ bh,
    float* __restrict__ out)
{
    int r = blockIdx.x, tid = threadIdx.x;
    const float* xr = x + (long)r * CC;
    float v[3];
    v[0] = xr[tid]; v[1] = xr[tid + 256]; v[2] = xr[tid + 512];
    float s  = v[0] + v[1] + v[2];
    float sq = v[0]*v[0] + v[1]*v[1] + v[2]*v[2];
#pragma unroll
    for (int off = 32; off > 0; off >>= 1) {
        s  += __shfl_down(s, off);
        sq += __shfl_down(sq, off);
    }
    __shared__ float ss[4], ssq[4];
    int w = tid >> 6;
    if ((tid & 63) == 0) { ss[w] = s; ssq[w] = sq; }
    __syncthreads();
    s  = ss[0] + ss[1] + ss[2] + ss[3];
    sq = ssq[0] + ssq[1] + ssq[2] + ssq[3];
    float mean = s * (1.0f / CC);
    float var  = sq * (1.0f / CC) - mean * mean;
    float rs   = rsqrtf(var + 1e-5f);

    float acc[16];
#pragma unroll
    for (int j = 0; j < 16; ++j) acc[j] = 0.f;
#pragma unroll
    for (int i = 0; i < 3; ++i) {
        int c = tid + i * 256;
        float xnv = (v[i] - mean) * rs * g[c] + bb[c];
        const float* wr = Wh + (long)c * 16;
#pragma unroll
        for (int j = 0; j < 16; ++j) acc[j] = fmaf(xnv, wr[j], acc[j]);
    }
#pragma unroll
    for (int off = 32; off > 0; off >>= 1)
#pragma unroll
        for (int j = 0; j < 16; ++j) acc[j] += __shfl_down(acc[j], off);
    __shared__ float red[4][16];
    if ((tid & 63) == 0)
#pragma unroll
        for (int j = 0; j < 16; ++j) red[w][j] = acc[j];
    __syncthreads();
    if (tid < 16)
        out[(long)r * 16 + tid] =
            red[0][tid] + red[1][tid] + red[2][tid] + red[3][tid] + bh[tid];
}

// ---------------------------------------------------------------- launch
extern "C" void kernel_launch(void* const* d_in, const int* in_sizes, int n_in,
                              void* d_out, int out_size, void* d_ws, size_t ws_size,
                              hipStream_t stream)
{
    const int*   idx  = (const int*)  d_in[0];
    const float* tok  = (const float*)d_in[1];
    const float* pos  = (const float*)d_in[2];
    const float* Wq   = (const float*)d_in[3];
    const float* Wk   = (const float*)d_in[4];
    const float* Wv   = (const float*)d_in[5];
    const float* Wo   = (const float*)d_in[6];
    const float* bo   = (const float*)d_in[7];
    const float* W1   = (const float*)d_in[8];
    const float* b1   = (const float*)d_in[9];
    const float* W2   = (const float*)d_in[10];
    const float* b2   = (const float*)d_in[11];
    const float* ln1g = (const float*)d_in[12];
    const float* ln1b = (const float*)d_in[13];
    const float* ln2g = (const float*)d_in[14];
    const float* ln2b = (const float*)d_in[15];
    const float* lnfg = (const float*)d_in[16];
    const float* lnfb = (const float*)d_in[17];
    const float* Wh   = (const float*)d_in[18];
    const float* bh   = (const float*)d_in[19];

    char* w = (char*)d_ws;
    float*          x    = (float*)w;           w += (long)BTOT * CC * 4;
    __hip_bfloat16* xn_b = (__hip_bfloat16*)w;  w += (long)BTOT * CC * 2;
    __hip_bfloat16* qkvb = (__hip_bfloat16*)w;  w += (long)BTOT * NQKV * 2;
    __hip_bfloat16* vT   = (__hip_bfloat16*)w;  w += (long)BTOT * CC * 2;
    __hip_bfloat16* o_b  = (__hip_bfloat16*)w;  w += (long)BTOT * CC * 2;
    __hip_bfloat16* hb   = (__hip_bfloat16*)w;  w += (long)BTOT * C4 * 2;
    __hip_bfloat16* wbuf = (__hip_bfloat16*)w;  w += (long)C4 * CC * 2;

    embed_k<<<BTOT, 256, 0, stream>>>(idx, tok, pos, x);

    const long wAtt = (long)HH * CC * HSZ;
    for (int l = 0; l < LL; ++l) {
        ln_b<<<BTOT, 256, 0, stream>>>(x, ln1g + l * CC, ln1b + l * CC, xn_b);

        cvt_qkvT<<<dim3(12, 36), 256, 0, stream>>>(
            Wq + l * wAtt, Wk + l * wAtt, Wv + l * wAtt, wbuf);
        gemm_bf16<0><<<dim3(NQKV / 128, BTOT / 128), 256, 0, stream>>>(
            xn_b, wbuf, qkvb, nullptr, nullptr, CC, CC, CC, NQKV);

        cvt_v<<<dim3(8, HH, 4), 256, 0, stream>>>(qkvb, vT);
        attn_mfma<<<dim3(TT / 16, HH, 4), 64, 0, stream>>>(qkvb, vT, o_b);

        cvtT_k<<<dim3(12, 12), 256, 0, stream>>>(Wo + (long)l * CC * CC, wbuf, CC, CC);
        gemm_bf16<3><<<dim3(CC / 128, BTOT / 128), 256, 0, stream>>>(
            o_b, wbuf, nullptr, x, bo + l * CC, CC, CC, CC, CC);

        ln_b<<<BTOT, 256, 0, stream>>>(x, ln2g + l * CC, ln2b + l * CC, xn_b);

        cvtT_k<<<dim3(48, 12), 256, 0, stream>>>(W1 + (long)l * CC * C4, wbuf, CC, C4);
        gemm_bf16<2><<<dim3(C4 / 128, BTOT / 128), 256, 0, stream>>>(
            xn_b, wbuf, hb, nullptr, b1 + l * C4, CC, CC, CC, C4);

        cvtT_k<<<dim3(12, 48), 256, 0, stream>>>(W2 + (long)l * C4 * CC, wbuf, C4, CC);
        gemm_bf16<3><<<dim3(CC / 128, BTOT / 128), 256, 0, stream>>>(
            hb, wbuf, nullptr, x, b2 + l * CC, C4, C4, C4, CC);
    }

    head_k<<<BTOT, 256, 0, stream>>>(x, lnfg, lnfb, Wh, bh, (float*)d_out);
}